// Round 1
// baseline (236.138 us; speedup 1.0000x reference)
//
#include <hip/hip_runtime.h>
#include <hip/hip_bf16.h>

typedef __attribute__((ext_vector_type(8))) short short8;
typedef __attribute__((ext_vector_type(4))) float f32x4;

static constexpr int NN = 64;
static constexpr int C  = 128;
static constexpr int H  = 56;
static constexpr int W  = 56;
static constexpr int HP = 58;          // padded spatial extent
static constexpr int KTOT = 1152;      // 9 * 128

__device__ __forceinline__ void gload16(const void* g, void* l) {
    __builtin_amdgcn_global_load_lds(
        (const __attribute__((address_space(1))) unsigned int*)g,
        (__attribute__((address_space(3))) unsigned int*)l, 16, 0, 0);
}

// ---------------------------------------------------------------------------
// Pack weights: w[o][c][kh][kw] * scale[o] -> Wp[o][tap*128 + c] (bf16),
// shift[o] = beta - mean*scale.  grid=128 (o), block=128 (c).
// ---------------------------------------------------------------------------
__global__ __launch_bounds__(128)
void pack_weights(const float* __restrict__ w, const float* __restrict__ g,
                  const float* __restrict__ b, const float* __restrict__ m,
                  const float* __restrict__ v, __hip_bfloat16* __restrict__ Wp,
                  float* __restrict__ shift)
{
    int o = blockIdx.x;
    int c = threadIdx.x;
    float scale = g[o] * rsqrtf(v[o] + 1e-5f);
    if (c == 0) shift[o] = b[o] - m[o] * scale;
    const float* ws = w + ((size_t)o * C + c) * 9;
    #pragma unroll
    for (int tap = 0; tap < 9; ++tap)
        Wp[(size_t)o * KTOT + tap * C + c] = __float2bfloat16(ws[tap] * scale);
}

// ---------------------------------------------------------------------------
// NCHW fp32 -> padded NHWC bf16.  grid = N*H blocks, 256 threads.
// ---------------------------------------------------------------------------
__global__ __launch_bounds__(256)
void transform_x(const float* __restrict__ x, __hip_bfloat16* __restrict__ Xp)
{
    __shared__ float t[C * 57];          // pitch 57 -> conflict-free both phases
    int bid = blockIdx.x;
    int n = bid / H, h = bid % H;
    int tid = threadIdx.x;

    // load 128c x 56w fp32, coalesced along w
    #pragma unroll
    for (int i = 0; i < 7; ++i) {
        int idx4 = i * 256 + tid;                 // 0..1791 float4s
        int c  = idx4 / 14;
        int wq = (idx4 % 14) * 4;
        const float* p = x + ((size_t)(n * C + c)) * (H * W) + h * W + wq;
        float4 vv = *(const float4*)p;
        t[c * 57 + wq + 0] = vv.x;
        t[c * 57 + wq + 1] = vv.y;
        t[c * 57 + wq + 2] = vv.z;
        t[c * 57 + wq + 3] = vv.w;
    }
    __syncthreads();
    // store NHWC bf16, coalesced along c
    #pragma unroll
    for (int i = 0; i < 28; ++i) {
        int idx = i * 256 + tid;                  // 0..7167
        int c = idx & 127, w = idx >> 7;
        float vv = t[c * 57 + w];
        Xp[(((size_t)n * HP + (h + 1)) * HP + (w + 1)) * C + c] = __float2bfloat16(vv);
    }
}

// ---------------------------------------------------------------------------
// Implicit-GEMM 3x3 conv, one (n,h) output row (M=64, 8 masked) x O=128.
// WHICH==0: D[m][o] = X*W, out = relu(D + shift) -> NHWC bf16 padded (Y1)
// WHICH==1: D[o][m] = W*X, out = relu(D + shift + identity) -> NCHW fp32
// LDS tiles XOR-swizzled: byte ^= ((row&7)<<4), applied on the pre-swizzled
// global SOURCE address for global_load_lds (linear dest) and on reads.
// ---------------------------------------------------------------------------
template<int WHICH>
__global__ __launch_bounds__(256)
void conv3x3_kernel(const __hip_bfloat16* __restrict__ Xp,
                    const __hip_bfloat16* __restrict__ Wp,
                    const float* __restrict__ shift,
                    const float* __restrict__ ident,
                    void* __restrict__ outp)
{
    __shared__ char s_x[68 * 256];   // [x-pos 0..67][128 c] bf16, swizzled
    __shared__ char s_w[128 * 256];  // [o][128 c] bf16 (one tap), swizzled

    const int tid  = threadIdx.x;
    const int wave = tid >> 6;
    const int lane = tid & 63;
    const int lr = lane & 15, lg = lane >> 4;

    const int bid = blockIdx.x;
    const int n = bid / H, h = bid % H;

    const char* xrow0 = (const char*)Xp + ((size_t)n * HP + h) * (HP * 256);

    f32x4 acc[8];
    #pragma unroll
    for (int i = 0; i < 8; ++i) acc[i] = (f32x4){0.f, 0.f, 0.f, 0.f};

    for (int kh = 0; kh < 3; ++kh) {
        // stage X positions x=0..65 of image row y=h+kh (17 KB, 17 1KB blocks)
        const char* xs = xrow0 + kh * (HP * 256);
        for (int blk = wave; blk < 17; blk += 4) {
            int dst = blk * 1024 + lane * 16;
            int src = dst ^ (((dst >> 8) & 7) << 4);
            gload16(xs + src, s_x + blk * 1024);
        }
        for (int kw = 0; kw < 3; ++kw) {
            const int tap = kh * 3 + kw;
            // stage weight tap slice [128 o][128 c] (32 KB, 32 1KB blocks)
            const char* wt = (const char*)Wp + tap * 256;
            #pragma unroll
            for (int i = 0; i < 8; ++i) {
                int blk = wave * 8 + i;
                int dst = blk * 1024 + lane * 16;
                int o   = dst >> 8;
                int col = (dst & 255) ^ ((o & 7) << 4);
                gload16(wt + (size_t)o * (KTOT * 2) + col, s_w + blk * 1024);
            }
            __syncthreads();

            #pragma unroll
            for (int kb = 0; kb < 4; ++kb) {
                const int cb = kb * 64 + lg * 16;     // c byte offset
                short8 xa[4], wb[2];
                #pragma unroll
                for (int sm = 0; sm < 4; ++sm) {
                    int row = sm * 16 + lr + kw;
                    int off = ((row << 8) + cb) ^ ((row & 7) << 4);
                    xa[sm] = *(const short8*)(s_x + off);
                }
                #pragma unroll
                for (int so = 0; so < 2; ++so) {
                    int o = wave * 32 + so * 16 + lr;
                    int off = ((o << 8) + cb) ^ ((o & 7) << 4);
                    wb[so] = *(const short8*)(s_w + off);
                }
                #pragma unroll
                for (int sm = 0; sm < 4; ++sm)
                    #pragma unroll
                    for (int so = 0; so < 2; ++so) {
                        if (WHICH == 0)
                            acc[sm * 2 + so] = __builtin_amdgcn_mfma_f32_16x16x32_bf16(
                                xa[sm], wb[so], acc[sm * 2 + so], 0, 0, 0);
                        else
                            acc[so * 4 + sm] = __builtin_amdgcn_mfma_f32_16x16x32_bf16(
                                wb[so], xa[sm], acc[so * 4 + sm], 0, 0, 0);
                    }
            }
            __syncthreads();
        }
    }

    if (WHICH == 0) {
        // D[m][o]: m = sm*16 + lg*4 + r, o = wave*32 + so*16 + lr
        __hip_bfloat16* o1 = (__hip_bfloat16*)outp;
        size_t rowbase = ((size_t)n * HP + (h + 1)) * HP;
        #pragma unroll
        for (int so = 0; so < 2; ++so) {
            int o = wave * 32 + so * 16 + lr;
            float sh = shift[o];
            #pragma unroll
            for (int sm = 0; sm < 4; ++sm) {
                f32x4 vv = acc[sm * 2 + so];
                #pragma unroll
                for (int r = 0; r < 4; ++r) {
                    int m = sm * 16 + lg * 4 + r;
                    if (m < W) {
                        float f = vv[r] + sh;
                        f = f > 0.f ? f : 0.f;
                        o1[(rowbase + (m + 1)) * C + o] = __float2bfloat16(f);
                    }
                }
            }
        }
    } else {
        // D[o][m]: o = wave*32 + so*16 + lg*4 + r, m = sm*16 + lr
        float* o2 = (float*)outp;
        #pragma unroll
        for (int so = 0; so < 2; ++so) {
            int obase = wave * 32 + so * 16 + lg * 4;
            f32x4 sh4 = *(const f32x4*)(shift + obase);
            #pragma unroll
            for (int sm = 0; sm < 4; ++sm) {
                f32x4 vv = acc[so * 4 + sm];
                int m = sm * 16 + lr;
                if (m < W) {
                    #pragma unroll
                    for (int r = 0; r < 4; ++r) {
                        int o = obase + r;
                        size_t idx = ((size_t)(n * C + o) * H + h) * W + m;
                        float f = vv[r] + sh4[r] + ident[idx];
                        o2[idx] = f > 0.f ? f : 0.f;
                    }
                }
            }
        }
    }
}

// ---------------------------------------------------------------------------
extern "C" void kernel_launch(void* const* d_in, const int* in_sizes, int n_in,
                              void* d_out, int out_size, void* d_ws, size_t ws_size,
                              hipStream_t stream)
{
    const float* x  = (const float*)d_in[0];
    const float* w1 = (const float*)d_in[1];
    const float* g1 = (const float*)d_in[2];
    const float* b1 = (const float*)d_in[3];
    const float* m1 = (const float*)d_in[4];
    const float* v1 = (const float*)d_in[5];
    const float* w2 = (const float*)d_in[6];
    const float* g2 = (const float*)d_in[7];
    const float* b2 = (const float*)d_in[8];
    const float* m2 = (const float*)d_in[9];
    const float* v2 = (const float*)d_in[10];
    float* out = (float*)d_out;

    char* ws = (char*)d_ws;
    const size_t PADBUF = (size_t)NN * HP * HP * C * 2;   // 55,107,584 B
    size_t oX  = 0;
    size_t oY  = oX + PADBUF + 32768;    // 32 KB slack for staging over-read
    size_t oW1 = oY + PADBUF + 32768;
    size_t oW2 = oW1 + (size_t)C * KTOT * 2;
    size_t oS1 = oW2 + (size_t)C * KTOT * 2;
    size_t oS2 = oS1 + 512;

    __hip_bfloat16* Xp  = (__hip_bfloat16*)(ws + oX);
    __hip_bfloat16* Y1  = (__hip_bfloat16*)(ws + oY);
    __hip_bfloat16* W1p = (__hip_bfloat16*)(ws + oW1);
    __hip_bfloat16* W2p = (__hip_bfloat16*)(ws + oW2);
    float* s1 = (float*)(ws + oS1);
    float* s2 = (float*)(ws + oS2);

    // zero padded buffers (halo = conv zero-padding)
    hipMemsetAsync(Xp, 0, PADBUF, stream);
    hipMemsetAsync(Y1, 0, PADBUF, stream);

    pack_weights<<<128, 128, 0, stream>>>(w1, g1, b1, m1, v1, W1p, s1);
    pack_weights<<<128, 128, 0, stream>>>(w2, g2, b2, m2, v2, W2p, s2);
    transform_x<<<NN * H, 256, 0, stream>>>(x, Xp);

    conv3x3_kernel<0><<<NN * H, 256, 0, stream>>>(Xp, W1p, s1, nullptr, (void*)Y1);
    conv3x3_kernel<1><<<NN * H, 256, 0, stream>>>(Y1, W2p, s2, x, (void*)out);
}